// Round 3
// baseline (216.240 us; speedup 1.0000x reference)
//
#include <hip/hip_runtime.h>

// Collider binary-tree sampling, DEPTH=9, TOTAL_VARS=510, f32 in/out.
// Level d (d=0..7) has width 2^(8-d); offset(d) = 512 - 2^(9-d).
//   d=0: x = eps ; d>0: x[j] = prev[2j] + prev[2j+1] + 0.1*eps[off+j]
//
// Round-2 lesson: row stride 2040 B is only 8B-aligned -> float2 global
// accesses capped us at 5.4 TB/s. Fix: stage 8 rows (16320 B = 255 x 64B,
// block-group IS 64B-aligned) through LDS with dense float4 global I/O;
// compute the tree in-place in LDS (level-0 output == input, each level
// overwrites its own eps slots).

#define TOTAL_VARS 510
#define ROWS_PER_BLOCK 8
#define BLOCK_FLOATS (ROWS_PER_BLOCK * TOTAL_VARS)   // 4080
#define BLOCK_F4     (BLOCK_FLOATS / 4)              // 1020
#define SIGMA 0.1f

__global__ __launch_bounds__(256) void collider_kernel(
    const float* __restrict__ eps,
    float* __restrict__ out,
    int N)
{
    __shared__ __align__(16) float lds[BLOCK_FLOATS];  // 16320 B

    const int tid = (int)threadIdx.x;
    const size_t base = (size_t)blockIdx.x * BLOCK_FLOATS;  // byte off = 16320*blk, 64B-aligned

    // ---- phase 1: dense aligned global -> LDS (float4)
    const float4* __restrict__ gin = reinterpret_cast<const float4*>(eps + base);
    float4* l4 = reinterpret_cast<float4*>(lds);
#pragma unroll
    for (int i = 0; i < 4; ++i) {
        const int idx = tid + i * 256;
        if (idx < BLOCK_F4) l4[idx] = gin[idx];
    }
    __syncthreads();

    // ---- phase 2: per-wave tree compute, in-place in LDS
    const int wave = tid >> 6;
    const int lane = tid & 63;

#pragma unroll
    for (int rr = 0; rr < 2; ++rr) {
        float* row = lds + (wave * 2 + rr) * TOTAL_VARS;  // 8B-aligned (2040B stride)

        // level 0: already in place (x = eps). Read leaves 4l..4l+3 (float2 pairs).
        const float2 a01 = *reinterpret_cast<const float2*>(row + 4 * lane);
        const float2 a23 = *reinterpret_cast<const float2*>(row + 4 * lane + 2);

        // level 1: offset 256, width 128
        const float2 e1 = *reinterpret_cast<const float2*>(row + 256 + 2 * lane);
        const float x1a = a01.x + a01.y + SIGMA * e1.x;
        const float x1b = a23.x + a23.y + SIGMA * e1.y;
        float2 o1; o1.x = x1a; o1.y = x1b;
        *reinterpret_cast<float2*>(row + 256 + 2 * lane) = o1;

        // level 2: offset 384, width 64
        const float e2 = row[384 + lane];
        const float x2 = x1a + x1b + SIGMA * e2;
        row[384 + lane] = x2;

        // levels 3..7: widths 32,16,8,4,2 via shuffle pair-gather
        float prev = x2;
#pragma unroll
        for (int d = 3; d < 8; ++d) {
            const int w   = 256 >> d;
            const int off = 512 - (512 >> d);
            const float a = __shfl(prev, 2 * lane);
            const float b = __shfl(prev, 2 * lane + 1);
            float e = 0.0f;
            if (lane < w) e = row[off + lane];
            const float v = a + b + SIGMA * e;
            if (lane < w) row[off + lane] = v;
            prev = v;
        }
    }
    __syncthreads();

    // ---- phase 3: dense aligned LDS -> global (float4)
    float4* __restrict__ gout = reinterpret_cast<float4*>(out + base);
#pragma unroll
    for (int i = 0; i < 4; ++i) {
        const int idx = tid + i * 256;
        if (idx < BLOCK_F4) gout[idx] = l4[idx];
    }
}

extern "C" void kernel_launch(void* const* d_in, const int* in_sizes, int n_in,
                              void* d_out, int out_size, void* d_ws, size_t ws_size,
                              hipStream_t stream) {
    const float* eps = (const float*)d_in[0];
    float* out = (float*)d_out;
    const int N = in_sizes[0] / TOTAL_VARS;  // 262144, divisible by 8

    const int blocks = N / ROWS_PER_BLOCK;   // 32768
    collider_kernel<<<blocks, 256, 0, stream>>>(eps, out, N);
}

// Round 4
// 204.682 us; speedup vs baseline: 1.0565x; 1.0565x over previous
//
#include <hip/hip_runtime.h>

// Collider binary-tree sampling, DEPTH=9, TOTAL_VARS=510, f32 in/out.
// Level d (d=0..7): width 2^(8-d), flat offset 512 - (512 >> d) ... i.e.
// offsets 0,256,384,448,480,496,504,508.
//   d=0: x = eps ; d>0: x[j] = prev[2j] + prev[2j+1] + 0.1*eps[off+j]
//
// Round-3 lessons: LDS staging with 2 barriers regressed (216 vs 198 us) ->
// reverted. This version keeps the direct in-register scheme but makes EVERY
// global access dense & wave-contiguous:
//   - L0: lane l owns leaves (2l,2l+1) and (128+2l,128+2l+1): dense float2.
//   - L1: pair values gathered by shuffle; dense float2 e-load/x-store.
//   - L3..L7 packed into disjoint lane ranges: ONE masked dense 62-float
//     e-load and ONE masked dense 62-float store replace 5+5 sparse ops.

#define TOTAL_VARS 510
#define SIGMA 0.1f

__global__ __launch_bounds__(256) void collider_kernel(
    const float* __restrict__ eps,
    float* __restrict__ out,
    int N)
{
    const int wid  = (int)((blockIdx.x * blockDim.x + threadIdx.x) >> 6);
    const int lane = (int)(threadIdx.x & 63);
    if (wid >= N) return;

    const float* __restrict__ ep = eps + (size_t)wid * TOTAL_VARS;
    float* __restrict__ op = out + (size_t)wid * TOTAL_VARS;

    // ---- level 0: dense float2 loads; copy through to out.
    const float2 f0 = *reinterpret_cast<const float2*>(ep + 2 * lane);        // leaves 2l, 2l+1
    const float2 f1 = *reinterpret_cast<const float2*>(ep + 128 + 2 * lane);  // leaves 128+2l, 128+2l+1
    *reinterpret_cast<float2*>(op + 2 * lane)       = f0;
    *reinterpret_cast<float2*>(op + 128 + 2 * lane) = f1;
    const float p0 = f0.x + f0.y;   // pair sum, pair index l
    const float p1 = f1.x + f1.y;   // pair sum, pair index 64 + l

    // ---- level 1 (offset 256, width 128): lane l computes x1[2l], x1[2l+1].
    const float2 e1 = *reinterpret_cast<const float2*>(ep + 256 + 2 * lane);
    const int i0 = (2 * lane) & 63;
    const int i1 = (2 * lane + 1) & 63;
    const float a0 = __shfl(p0, i0), a1 = __shfl(p0, i1);   // pairs 0..63
    const float b0 = __shfl(p1, i0), b1 = __shfl(p1, i1);   // pairs 64..127
    const float pe = (lane < 32) ? a0 : b0;                 // pair[2l]
    const float po = (lane < 32) ? a1 : b1;                 // pair[2l+1]
    const float x1e = pe + SIGMA * e1.x;
    const float x1o = po + SIGMA * e1.y;
    float2 o1; o1.x = x1e; o1.y = x1o;
    *reinterpret_cast<float2*>(op + 256 + 2 * lane) = o1;

    // ---- level 2 (offset 384, width 64): lane l holds x2[l].
    const float e2 = ep[384 + lane];
    float v = (x1e + x1o) + SIGMA * e2;
    op[384 + lane] = v;

    // ---- tail eps for levels 3..7 (offsets 448..509), one dense masked load.
    // lane-range per level d: [64 - (512>>d), +width) = [0..31],[32..47],[48..55],[56..59],[60..61]
    float et = 0.0f;
    if (lane < 62) et = ep[448 + lane];

    // ---- levels 3..7 packed into disjoint lane ranges; v carries each
    // level's value in its lanes (previous level's lanes stay intact).
#pragma unroll
    for (int d = 3; d < 8; ++d) {
        const int w     = 256 >> d;
        const int lbase = 64 - (512 >> d);                  // 0,32,48,56,60
        const int pbase = (d == 3) ? 0 : (64 - (1024 >> d)); // 0,0,32,48,56
        const int j   = lane - lbase;
        const int src = (pbase + 2 * j) & 63;
        const float a = __shfl(v, src);
        const float b = __shfl(v, (src + 1) & 63);
        const float nv = a + b + SIGMA * et;
        const bool act = (lane >= lbase) && (lane < lbase + w);
        v = act ? nv : v;
    }
    if (lane < 62) op[448 + lane] = v;   // one dense masked store for all 5 levels
}

extern "C" void kernel_launch(void* const* d_in, const int* in_sizes, int n_in,
                              void* d_out, int out_size, void* d_ws, size_t ws_size,
                              hipStream_t stream) {
    const float* eps = (const float*)d_in[0];
    float* out = (float*)d_out;
    const int N = in_sizes[0] / TOTAL_VARS;  // 262144

    const int threads = 256;                 // 4 waves = 4 rows per block
    const int rows_per_block = threads / 64;
    const int blocks = (N + rows_per_block - 1) / rows_per_block;
    collider_kernel<<<blocks, threads, 0, stream>>>(eps, out, N);
}

// Round 5
// 196.414 us; speedup vs baseline: 1.1009x; 1.0421x over previous
//
#include <hip/hip_runtime.h>

// Collider binary-tree sampling, DEPTH=9, TOTAL_VARS=510, f32 in/out.
// Level d (d=0..7): width 2^(8-d), flat offset 512-(512>>d).
//   d=0: x = eps ; d>0: x[j] = prev[2j] + prev[2j+1] + 0.1*eps[off+j]
//
// Round-4 design: wave-private LDS staging, ZERO barriers.
//  - One wave owns TWO consecutive rows: 1020 floats = 4080 B = 255 x 16 B,
//    so every row-pair base is 16B-aligned -> all global I/O is dense float4.
//  - Phase 1: global -> own LDS region (255 float4 / wave).
//  - Phase 2: round-2 tree compute in place in LDS (L0 output == input, so
//    level 0 needs no store; deeper levels overwrite their eps slots).
//  - Phase 3: own LDS region -> global (255 float4 / wave).
//  No __syncthreads: each wave touches only its own LDS; same-wave
//  ds_write->ds_read ordering is enforced by compiler lgkmcnt waits.
// (Round-3 lesson: block-wide barriers around staging cost ~18 us; this
//  tests aligned float4 I/O without them.)

#define TOTAL_VARS 510
#define SIGMA 0.1f

__global__ __launch_bounds__(256) void collider_kernel(
    const float* __restrict__ eps,
    float* __restrict__ out,
    int N)
{
    __shared__ __align__(16) float lds[4 * 1020];   // 16320 B, per-wave 4080 B (16B-aligned)

    const int tid  = (int)threadIdx.x;
    const int wave = tid >> 6;
    const int lane = tid & 63;

    const size_t pair = (size_t)blockIdx.x * 4 + wave;      // row-pair index (N/2 total)
    const float* __restrict__ gin = eps + pair * 1020;
    float* __restrict__ gout      = out + pair * 1020;
    float* lw = lds + wave * 1020;

    // ---- phase 1: global -> LDS, dense float4 (255 per wave)
    const float4* __restrict__ g4 = reinterpret_cast<const float4*>(gin);
    float4* l4 = reinterpret_cast<float4*>(lw);
#pragma unroll
    for (int c = 0; c < 4; ++c) {
        const int idx = c * 64 + lane;
        if (idx < 255) l4[idx] = g4[idx];
    }

    // ---- phase 2: tree compute per row, in place in LDS
#pragma unroll
    for (int rr = 0; rr < 2; ++rr) {
        float* row = lw + rr * TOTAL_VARS;   // 2040 B stride: 8B-aligned, float2 ok

        // level 0: x = eps, already in place; read leaves 4l..4l+3
        const float2 a01 = *reinterpret_cast<const float2*>(row + 4 * lane);
        const float2 a23 = *reinterpret_cast<const float2*>(row + 4 * lane + 2);

        // level 1 (offset 256, width 128)
        const float2 e1 = *reinterpret_cast<const float2*>(row + 256 + 2 * lane);
        const float x1a = a01.x + a01.y + SIGMA * e1.x;
        const float x1b = a23.x + a23.y + SIGMA * e1.y;
        float2 o1; o1.x = x1a; o1.y = x1b;
        *reinterpret_cast<float2*>(row + 256 + 2 * lane) = o1;

        // level 2 (offset 384, width 64)
        const float e2 = row[384 + lane];
        float prev = x1a + x1b + SIGMA * e2;
        row[384 + lane] = prev;

        // levels 3..7: widths 32,16,8,4,2 via shuffle pair-gather
#pragma unroll
        for (int d = 3; d < 8; ++d) {
            const int w   = 256 >> d;
            const int off = 512 - (512 >> d);
            const float a = __shfl(prev, 2 * lane);
            const float b = __shfl(prev, 2 * lane + 1);
            float e = 0.0f;
            if (lane < w) e = row[off + lane];
            const float v = a + b + SIGMA * e;
            if (lane < w) row[off + lane] = v;
            prev = v;
        }
    }

    // ---- phase 3: LDS -> global, dense float4 (255 per wave)
#pragma unroll
    for (int c = 0; c < 4; ++c) {
        const int idx = c * 64 + lane;
        if (idx < 255) *reinterpret_cast<float4*>(gout + 4 * idx) = l4[idx];
    }
}

extern "C" void kernel_launch(void* const* d_in, const int* in_sizes, int n_in,
                              void* d_out, int out_size, void* d_ws, size_t ws_size,
                              hipStream_t stream) {
    const float* eps = (const float*)d_in[0];
    float* out = (float*)d_out;
    const int N = in_sizes[0] / TOTAL_VARS;  // 262144 (even)

    const int pairs = N / 2;                 // 131072 row-pairs
    const int blocks = pairs / 4;            // 4 waves per block -> 32768 blocks
    collider_kernel<<<blocks, 256, 0, stream>>>(eps, out, N);
}